// Round 12
// baseline (1165.202 us; speedup 1.0000x reference)
//
#include <hip/hip_runtime.h>

// NaryTreeLSTMCell: B=32, L=512, E=H=1024.  Outputs h_out, c_out (f32, 2x16384x1024).
//
//   gx = x @ [W_ioux | W_fx]; gh = h0 @ [Wiouh0[:,:H]|Wiouh1[:,:H]|Wfh0+Wfh1|Wfh2+Wfh3]+b
//   add/fc via per-batch CSR gathers; gates -> c_new,h_new; compaction via sel[].
//
// Rounds 3-11: every LDS-staged schedule (bank-conflict-free, volume-minimal,
// counted-vmcnt, 1-barrier, 3-slot, 2 blocks/CU) pins at MfmaUtil 35-41% /
// ~300us. r9 ablation: even MFMA+barrier-skeleton alone = 220us vs 132us pipe
// floor. The invariant is LDS staging + barrier coupling itself. This round
// removes it: ZERO-LDS ZERO-BARRIER register GEMM. Weights pre-transposed
// [N][K] make each lane's MFMA fragment a contiguous 16B global run -> load
// fragments directly from L2 (global_load_dwordx4), no __shared__, no barriers
// in the K-loop. Each wave independently owns a 64x64 output tile; blocks are
// 4-wave containers for L1/L2 locality (XCD swizzle keeps B panel L2-resident).
// L2 traffic ~4.3GB =~ 60-125us < 132us MFMA floor -> affordable.

#define ROWS 16384
#define HID  1024
#define KDIM 1024
#define NCOLS 4096

typedef __attribute__((ext_vector_type(4))) int            i32x4;
typedef __attribute__((ext_vector_type(4))) float          f32x4;
typedef __attribute__((ext_vector_type(4))) unsigned short u16x4;

__device__ __forceinline__ unsigned short f2bf(float f) {
  unsigned u = __float_as_uint(f);
  unsigned r = 0x7FFFu + ((u >> 16) & 1u);
  return (unsigned short)((u + r) >> 16);
}
__device__ __forceinline__ float bf2f(unsigned short v) {
  return __uint_as_float(((unsigned)v) << 16);
}
__device__ __forceinline__ float sigmoidf_(float x) {
  return 1.0f / (1.0f + __expf(-x));
}
__device__ __forceinline__ void mfma_bf16(f32x4& acc, i32x4 a, i32x4 b) {
  asm volatile("v_mfma_f32_16x16x32_bf16 %0, %1, %2, %0"
               : "+v"(acc) : "v"(a), "v"(b));
}

// ---- weight packing: transposed bf16 panels [N=4096][K=1024] ----

__global__ void pack_wx(const float* __restrict__ Wioux, const float* __restrict__ Wfx,
                        unsigned short* __restrict__ Wxt) {
  __shared__ float t[32][33];
  const int n0 = blockIdx.x * 32, k0 = blockIdx.y * 32;
  const int tx = threadIdx.x, ty = threadIdx.y;
  const int n = n0 + tx, k = k0 + ty;
  float v = (n < 3072) ? Wioux[(size_t)k * 3072 + n]
                       : Wfx[(size_t)k * 1024 + (n - 3072)];
  t[ty][tx] = v;
  __syncthreads();
  Wxt[(size_t)(n0 + ty) * KDIM + (k0 + tx)] = f2bf(t[tx][ty]);
}

__global__ void pack_wh(const float* __restrict__ Wiouh, const float* __restrict__ Wfh,
                        unsigned short* __restrict__ Wht) {
  __shared__ float t[32][33];
  const int n0 = blockIdx.x * 32, k0 = blockIdx.y * 32;
  const int tx = threadIdx.x, ty = threadIdx.y;
  const int n = n0 + tx, k = k0 + ty;
  float v;
  if (n < 1024)      v = Wiouh[(size_t)k * 3072 + n];
  else if (n < 2048) v = Wiouh[3145728u + (size_t)k * 3072 + (n - 1024)];
  else if (n < 3072) { const int c = n - 2048;
    v = Wfh[(size_t)k * 1024 + c] + Wfh[1048576u + (size_t)k * 1024 + c]; }
  else { const int c = n - 3072;
    v = Wfh[2097152u + (size_t)k * 1024 + c] + Wfh[3145728u + (size_t)k * 1024 + c]; }
  t[ty][tx] = v;
  __syncthreads();
  Wht[(size_t)(n0 + ty) * KDIM + (k0 + tx)] = f2bf(t[tx][ty]);
}

__global__ void pack_bias(const float* __restrict__ b_iouh, const float* __restrict__ b_fh,
                          float* __restrict__ bh) {
  const int n = blockIdx.x * 1024 + threadIdx.x;
  float v;
  if (n < 1024)      v = b_iouh[n];
  else if (n < 2048) v = b_iouh[3072 + (n - 1024)];
  else if (n < 3072) { const int c = n - 2048; v = b_fh[c] + b_fh[1024 + c]; }
  else { const int c = n - 3072; v = b_fh[2048 + c] + b_fh[3072 + c]; }
  bh[n] = v;
}

__global__ void convert_bf16(const float* __restrict__ x, const float* __restrict__ h0,
                             unsigned short* __restrict__ xb, unsigned short* __restrict__ hb) {
  const size_t i = ((size_t)blockIdx.x * 256 + threadIdx.x) * 4;
  const float4 a = *(const float4*)&x[i];
  const float4 b = *(const float4*)&h0[i];
  u16x4 av = { f2bf(a.x), f2bf(a.y), f2bf(a.z), f2bf(a.w) };
  u16x4 bv = { f2bf(b.x), f2bf(b.y), f2bf(b.z), f2bf(b.w) };
  *(u16x4*)&xb[i] = av;
  *(u16x4*)&hb[i] = bv;
}

// ---- zero-LDS zero-barrier GEMM: each wave owns a 64x64 tile; fragments
// loaded straight from global (L2). No __shared__, no s_barrier in K-loop.
__global__ __launch_bounds__(256, 3)
void gemm_nl(const unsigned short* __restrict__ xb, const unsigned short* __restrict__ hb,
             const unsigned short* __restrict__ Wxt, const unsigned short* __restrict__ Wht,
             unsigned short* __restrict__ gxb, unsigned short* __restrict__ ghb,
             const float* __restrict__ bhv) {
  const unsigned short* A;
  const unsigned short* Bt;
  unsigned short* Cp;
  const float* bias;
  if (blockIdx.z == 0) { A = xb; Bt = Wxt; Cp = gxb; bias = nullptr; }
  else                 { A = hb; Bt = Wht; Cp = ghb; bias = bhv; }

  // T1 XCD swizzle (bijective: grid 32x128, ny%8==0); y-major within chunk so
  // consecutive blocks share the B panel (L2-resident) and stream A.
  int bx = blockIdx.x, by = blockIdx.y;
  {
    const int n = blockIdx.x + gridDim.x * blockIdx.y;
    const int xcd = n & 7, idx = n >> 3;
    const int ych = gridDim.y >> 3;           // 16
    bx = idx / ych;
    by = xcd * ych + (idx % ych);
  }
  const int tid = threadIdx.x, w = tid >> 6, lane = tid & 63;
  const int wr = w & 1, wc = w >> 1;
  const int m0 = lane & 15, kg = lane >> 4;
  const int bm = by * 128 + wr * 64;
  const int bn = bx * 128 + wc * 64;

  // A/B fragment base: lane (m0,kg) -> row bm+m0 (+i*16), k-chunk kg*8 (+t*32).
  // A and B use the SAME (lane,elem)->k mapping, so HW k-permutation cancels.
  const unsigned short* Ap = A  + (size_t)(bm + m0) * KDIM + kg * 8;
  const unsigned short* Bp = Bt + (size_t)(bn + m0) * KDIM + kg * 8;

  f32x4 acc[4][4] = {};
#pragma unroll 2
  for (int t = 0; t < 32; ++t) {
    const int k0 = t * 32;
    i32x4 af[4], bf[4];
#pragma unroll
    for (int i = 0; i < 4; ++i)
      af[i] = *(const i32x4*)(Ap + (size_t)i * 16 * KDIM + k0);
#pragma unroll
    for (int j = 0; j < 4; ++j)
      bf[j] = *(const i32x4*)(Bp + (size_t)j * 16 * KDIM + k0);
#pragma unroll
    for (int i = 0; i < 4; ++i)
#pragma unroll
      for (int j = 0; j < 4; ++j)
        mfma_bf16(acc[i][j], af[i], bf[j]);
  }

  // C/D layout (m89/m91): col = lane&15, row = 4*(lane>>4)+reg.
  const int rg = kg * 4;
#pragma unroll
  for (int i = 0; i < 4; ++i) {
#pragma unroll
    for (int j = 0; j < 4; ++j) {
      const int col = bn + j * 16 + m0;
      const float bv = bias ? bias[col] : 0.0f;
      const int row = bm + i * 16 + rg;
#pragma unroll
      for (int r = 0; r < 4; ++r)
        Cp[(size_t)(row + r) * NCOLS + col] = f2bf(acc[i][j][r] + bv);
    }
  }
}

// ---- global mask compaction scan ----
__global__ void scan_mask(const int* __restrict__ idd, int* __restrict__ sel,
                          int* __restrict__ mcount) {
  __shared__ int ps[1024];
  const int t = threadIdx.x;
  int loc[16];
  int cnt = 0;
#pragma unroll
  for (int i = 0; i < 16; ++i) {
    const int v = (idd[t * 16 + i] != 0) ? 1 : 0;
    loc[i] = v; cnt += v;
  }
  ps[t] = cnt;
  __syncthreads();
  for (int off = 1; off < 1024; off <<= 1) {
    const int add = (t >= off) ? ps[t - off] : 0;
    __syncthreads();
    ps[t] += add;
    __syncthreads();
  }
  int rank = (t == 0) ? 0 : ps[t - 1];
#pragma unroll
  for (int i = 0; i < 16; ++i)
    if (loc[i]) sel[rank++] = t * 16 + i;
  if (t == 1023) *mcount = ps[1023];
}

// ---- per-batch CSR (deterministic, sorted contributor lists) ----
__global__ void build_csr(const int* __restrict__ idd, const int* __restrict__ idr,
                          const int* __restrict__ idl,
                          int* __restrict__ ofsD, int* __restrict__ ofsR, int* __restrict__ ofsL,
                          int* __restrict__ lstD, int* __restrict__ lstR, int* __restrict__ lstL) {
  __shared__ int sidx[512];
  __shared__ int scan[512];
  const int b = blockIdx.x, t = threadIdx.x;
  const int gb = b << 9;
  const int* const srcs[3] = { idd, idr, idl };
  int* const ofss[3] = { ofsD, ofsR, ofsL };
  int* const lsts[3] = { lstD, lstR, lstL };
  for (int a = 0; a < 3; ++a) {
    sidx[t] = srcs[a][gb + t];
    scan[t] = 0;
    __syncthreads();
    atomicAdd(&scan[sidx[t]], 1);
    __syncthreads();
    int v = scan[t];
    for (int off = 1; off < 512; off <<= 1) {
      const int add = (t >= off) ? scan[t - off] : 0;
      __syncthreads();
      scan[t] += add;
      __syncthreads();
    }
    const int start = scan[t] - v;
    ofss[a][b * 513 + t] = start;
    if (t == 511) ofss[a][b * 513 + 512] = scan[511];
    int pos = start;
    for (int l = 0; l < 512; ++l)
      if (sidx[l] == t) lsts[a][gb + (pos++)] = l;
    __syncthreads();
  }
}

// ---- fused epilogue: gather-add + f-gate + activations + compaction write ----
__global__ __launch_bounds__(256)
void fused_final(const unsigned short* __restrict__ gxb, const unsigned short* __restrict__ ghb,
                 const float* __restrict__ h0, const float* __restrict__ c0,
                 const int* __restrict__ idd, const int* __restrict__ idr,
                 const int* __restrict__ idl,
                 const int* __restrict__ ofsR, const int* __restrict__ lstR,
                 const int* __restrict__ ofsL, const int* __restrict__ lstL,
                 const int* __restrict__ ofsD, const int* __restrict__ lstD,
                 const int* __restrict__ sel, const int* __restrict__ mcount,
                 float* __restrict__ hout, float* __restrict__ cout, int r0) {
  const int r = blockIdx.x;
  const int g = r0 + r;
  const int j = g & 511;
  const int bb = g >> 9;
  const int lbase = (r >> 9) << 9;
  const int ob = bb * 513;
  const int lb = bb << 9;
  const int c = threadIdx.x << 2;

  float a0 = 0.f, a1 = 0.f, a2 = 0.f, a3 = 0.f;
  for (int q = ofsR[ob + j], e = ofsR[ob + j + 1]; q < e; ++q) {
    const int l = lstR[lb + q];
    const u16x4 v = *(const u16x4*)&ghb[(size_t)(lbase + l) * NCOLS + c];
    a0 += bf2f(v[0]); a1 += bf2f(v[1]); a2 += bf2f(v[2]); a3 += bf2f(v[3]);
  }
  for (int q = ofsL[ob + j], e = ofsL[ob + j + 1]; q < e; ++q) {
    const int l = lstL[lb + q];
    const u16x4 v = *(const u16x4*)&ghb[(size_t)(lbase + l) * NCOLS + 1024 + c];
    a0 += bf2f(v[0]); a1 += bf2f(v[1]); a2 += bf2f(v[2]); a3 += bf2f(v[3]);
  }

  const u16x4 fx4 = *(const u16x4*)&gxb[(size_t)r * NCOLS + 3072 + c];
  const float fx0 = bf2f(fx4[0]), fx1 = bf2f(fx4[1]), fx2 = bf2f(fx4[2]), fx3 = bf2f(fx4[3]);
  float fc0 = 0.f, fc1 = 0.f, fc2 = 0.f, fc3 = 0.f;
  for (int q = ofsD[ob + j], e = ofsD[ob + j + 1]; q < e; ++q) {
    const int l = lstD[lb + q];
    const int jr = idr[lb + l], jl = idl[lb + l];
    const u16x4 rv = *(const u16x4*)&ghb[(size_t)(lbase + jr) * NCOLS + 2048 + c];
    const u16x4 lv = *(const u16x4*)&ghb[(size_t)(lbase + jl) * NCOLS + 3072 + c];
    const float4 cc = *(const float4*)&c0[(size_t)(lb + l) * HID + c];
    fc0 += sigmoidf_(fx0 + bf2f(rv[0]) + bf2f(lv[0])) * cc.x;
    fc1 += sigmoidf_(fx1 + bf2f(rv[1]) + bf2f(lv[1])) * cc.y;
    fc2 += sigmoidf_(fx2 + bf2f(rv[2]) + bf2f(lv[2])) * cc.z;
    fc3 += sigmoidf_(fx3 + bf2f(rv[3]) + bf2f(lv[3])) * cc.w;
  }

  const u16x4 vi = *(const u16x4*)&gxb[(size_t)r * NCOLS + c];
  const u16x4 vo = *(const u16x4*)&gxb[(size_t)r * NCOLS + 1024 + c];
  const u16x4 vu = *(const u16x4*)&gxb[(size_t)r * NCOLS + 2048 + c];
  float4 hn, cn;
  {
    const float ig = sigmoidf_(bf2f(vi[0]) + a0), og = sigmoidf_(bf2f(vo[0]));
    cn.x = ig * tanhf(bf2f(vu[0])) + fc0; hn.x = og * tanhf(cn.x);
  }
  {
    const float ig = sigmoidf_(bf2f(vi[1]) + a1), og = sigmoidf_(bf2f(vo[1]));
    cn.y = ig * tanhf(bf2f(vu[1])) + fc1; hn.y = og * tanhf(cn.y);
  }
  {
    const float ig = sigmoidf_(bf2f(vi[2]) + a2), og = sigmoidf_(bf2f(vo[2]));
    cn.z = ig * tanhf(bf2f(vu[2])) + fc2; hn.z = og * tanhf(cn.z);
  }
  {
    const float ig = sigmoidf_(bf2f(vi[3]) + a3), og = sigmoidf_(bf2f(vo[3]));
    cn.w = ig * tanhf(bf2f(vu[3])) + fc3; hn.w = og * tanhf(cn.w);
  }

  if (idd[g] == 0) {
    *(float4*)&hout[(size_t)g * HID + c] = *(const float4*)&h0[(size_t)g * HID + c];
    *(float4*)&cout[(size_t)g * HID + c] = *(const float4*)&c0[(size_t)g * HID + c];
  }
  const int m = *mcount;
  if (g < m) {
    const int o = sel[g];
    *(float4*)&hout[(size_t)o * HID + c] = hn;
    *(float4*)&cout[(size_t)o * HID + c] = cn;
  }
}

extern "C" void kernel_launch(void* const* d_in, const int* in_sizes, int n_in,
                              void* d_out, int out_size, void* d_ws, size_t ws_size,
                              hipStream_t stream) {
  const float* x      = (const float*)d_in[0];
  const float* h0     = (const float*)d_in[1];
  const float* c0     = (const float*)d_in[2];
  const float* W_ioux = (const float*)d_in[3];
  const float* W_iouh = (const float*)d_in[4];
  const float* b_iouh = (const float*)d_in[5];
  const float* W_fx   = (const float*)d_in[6];
  const float* W_fh   = (const float*)d_in[7];
  const float* b_fh   = (const float*)d_in[8];
  const int* idd      = (const int*)d_in[9];
  const int* idr      = (const int*)d_in[10];
  const int* idl      = (const int*)d_in[11];
  float* hout = (float*)d_out;
  float* cout = hout + (size_t)ROWS * HID;

  // fixed region (~17.3 MB)
  char* ws = (char*)d_ws;
  unsigned short* Wxt  = (unsigned short*)(ws);
  unsigned short* Wht  = (unsigned short*)(ws + 8388608u);
  float*          bh   = (float*)(ws + 16777216u);
  int*            sel  = (int*)(ws + 16793600u);
  int*            mcnt = (int*)(ws + 16859136u);
  int*            ofsD = (int*)(ws + 16859392u);
  int*            ofsR = (int*)(ws + 16925184u);
  int*            ofsL = (int*)(ws + 16990976u);
  int*            lstD = (int*)(ws + 17056768u);
  int*            lstR = (int*)(ws + 17122304u);
  int*            lstL = (int*)(ws + 17187840u);
  const size_t    base = 17253376u;

  // chunk size: largest power-of-two divisor of 32 fitting ws (10 MiB per batch)
  int C = 32;
  while (C > 1 && base + 10485760ull * (size_t)C > ws_size) C >>= 1;
  const int R = 512 * C;

  char* p = ws + base;
  unsigned short* xb  = (unsigned short*)p;  p += 1048576ull * C;
  unsigned short* hb  = (unsigned short*)p;  p += 1048576ull * C;
  unsigned short* gxb = (unsigned short*)p;  p += 4194304ull * C;
  unsigned short* ghb = (unsigned short*)p;

  pack_wx<<<dim3(128, 32), dim3(32, 32), 0, stream>>>(W_ioux, W_fx, Wxt);
  pack_wh<<<dim3(128, 32), dim3(32, 32), 0, stream>>>(W_iouh, W_fh, Wht);
  pack_bias<<<4, 1024, 0, stream>>>(b_iouh, b_fh, bh);
  scan_mask<<<1, 1024, 0, stream>>>(idd, sel, mcnt);
  build_csr<<<32, 512, 0, stream>>>(idd, idr, idl, ofsD, ofsR, ofsL, lstD, lstR, lstL);

  for (int b0 = 0; b0 < 32; b0 += C) {
    const size_t r0 = (size_t)b0 * 512;
    convert_bf16<<<R, 256, 0, stream>>>(x + r0 * HID, h0 + r0 * HID, xb, hb);
    gemm_nl<<<dim3(NCOLS / 128, R / 128, 2), 256, 0, stream>>>(xb, hb, Wxt, Wht, gxb, ghb, bh);
    fused_final<<<R, 256, 0, stream>>>(gxb, ghb, h0, c0, idd, idr, idl,
                                       ofsR, lstR, ofsL, lstL, ofsD, lstD,
                                       sel, mcnt, hout, cout, (int)r0);
  }
}

// Round 13
// 541.814 us; speedup vs baseline: 2.1506x; 2.1506x over previous
//
#include <hip/hip_runtime.h>

// NaryTreeLSTMCell: B=32, L=512, E=H=1024.  Outputs h_out, c_out (f32, 2x16384x1024).
//
//   gx = x @ [W_ioux | W_fx]; gh = h0 @ [Wiouh0[:,:H]|Wiouh1[:,:H]|Wfh0+Wfh1|Wfh2+Wfh3]+b
//   add/fc via per-batch CSR gathers; gates -> c_new,h_new; compaction via sel[].
//
// Round-12 model (fits ALL rounds): LDS-read and MFMA cycles are ADDITIVE
// (convoy): every variant read phase-p frags immediately before phase-p MFMAs
// -> wave-internal serialization; barriers phase-lock waves -> pipes alternate
// idle. Fix: FRAG-READ LOOKAHEAD. 4-slot BK=32 skeleton (r10); during tile t,
// read tile t+1's 12 frags into ping-pong reg set Y, then MM(t) on set X ->
// compiler emits lgkmcnt(12), LDS pipe fills under the MFMA cluster.
// Retirement shifted one tile early (vmcnt(4): t+2 retired at end of t) so
// the pre-read is barrier-published-safe. 1 barrier/tile.

#define ROWS 16384
#define HID  1024
#define KDIM 1024
#define NCOLS 4096
#define BM 256
#define BN 256

typedef __attribute__((ext_vector_type(4))) int            i32x4;
typedef __attribute__((ext_vector_type(4))) float          f32x4;
typedef __attribute__((ext_vector_type(4))) unsigned short u16x4;
typedef __attribute__((ext_vector_type(8))) unsigned short u16x8;

__device__ __forceinline__ unsigned short f2bf(float f) {
  unsigned u = __float_as_uint(f);
  unsigned r = 0x7FFFu + ((u >> 16) & 1u);
  return (unsigned short)((u + r) >> 16);
}
__device__ __forceinline__ float bf2f(unsigned short v) {
  return __uint_as_float(((unsigned)v) << 16);
}
__device__ __forceinline__ float sigmoidf_(float x) {
  return 1.0f / (1.0f + __expf(-x));
}
__device__ __forceinline__ void gload16(const void* g, void* l) {
  __builtin_amdgcn_global_load_lds(
      (const __attribute__((address_space(1))) void*)g,
      (__attribute__((address_space(3))) void*)l, 16, 0, 0);
}
__device__ __forceinline__ void mfma_bf16(f32x4& acc, i32x4 a, i32x4 b) {
  asm volatile("v_mfma_f32_16x16x32_bf16 %0, %1, %2, %0"
               : "+v"(acc) : "v"(a), "v"(b));
}

// ---- weight packing: transposed bf16 panels [N=4096][K=1024] ----

__global__ void pack_wx(const float* __restrict__ Wioux, const float* __restrict__ Wfx,
                        unsigned short* __restrict__ Wxt) {
  __shared__ float t[32][33];
  const int n0 = blockIdx.x * 32, k0 = blockIdx.y * 32;
  const int tx = threadIdx.x, ty = threadIdx.y;
  const int n = n0 + tx, k = k0 + ty;
  float v = (n < 3072) ? Wioux[(size_t)k * 3072 + n]
                       : Wfx[(size_t)k * 1024 + (n - 3072)];
  t[ty][tx] = v;
  __syncthreads();
  Wxt[(size_t)(n0 + ty) * KDIM + (k0 + tx)] = f2bf(t[tx][ty]);
}

__global__ void pack_wh(const float* __restrict__ Wiouh, const float* __restrict__ Wfh,
                        unsigned short* __restrict__ Wht) {
  __shared__ float t[32][33];
  const int n0 = blockIdx.x * 32, k0 = blockIdx.y * 32;
  const int tx = threadIdx.x, ty = threadIdx.y;
  const int n = n0 + tx, k = k0 + ty;
  float v;
  if (n < 1024)      v = Wiouh[(size_t)k * 3072 + n];
  else if (n < 2048) v = Wiouh[3145728u + (size_t)k * 3072 + (n - 1024)];
  else if (n < 3072) { const int c = n - 2048;
    v = Wfh[(size_t)k * 1024 + c] + Wfh[1048576u + (size_t)k * 1024 + c]; }
  else { const int c = n - 3072;
    v = Wfh[2097152u + (size_t)k * 1024 + c] + Wfh[3145728u + (size_t)k * 1024 + c]; }
  t[ty][tx] = v;
  __syncthreads();
  Wht[(size_t)(n0 + ty) * KDIM + (k0 + tx)] = f2bf(t[tx][ty]);
}

__global__ void pack_bias(const float* __restrict__ b_iouh, const float* __restrict__ b_fh,
                          float* __restrict__ bh) {
  const int n = blockIdx.x * 1024 + threadIdx.x;
  float v;
  if (n < 1024)      v = b_iouh[n];
  else if (n < 2048) v = b_iouh[3072 + (n - 1024)];
  else if (n < 3072) { const int c = n - 2048; v = b_fh[c] + b_fh[1024 + c]; }
  else { const int c = n - 3072; v = b_fh[2048 + c] + b_fh[3072 + c]; }
  bh[n] = v;
}

__global__ void convert_bf16(const float* __restrict__ x, const float* __restrict__ h0,
                             unsigned short* __restrict__ xb, unsigned short* __restrict__ hb) {
  const size_t i = ((size_t)blockIdx.x * 256 + threadIdx.x) * 4;
  const float4 a = *(const float4*)&x[i];
  const float4 b = *(const float4*)&h0[i];
  u16x4 av = { f2bf(a.x), f2bf(a.y), f2bf(a.z), f2bf(a.w) };
  u16x4 bv = { f2bf(b.x), f2bf(b.y), f2bf(b.z), f2bf(b.w) };
  *(u16x4*)&xb[i] = av;
  *(u16x4*)&hb[i] = bv;
}

// stageR: one 128-row round into a slot; 1 gload16/thread (512 thr -> 128 rows
// x 64B). Global seg XOR-swizzled by (r>>1)&3; LDS linear (gload_lds rule).
__device__ __forceinline__ void stageR(const unsigned short* __restrict__ gp,
                                       unsigned short* __restrict__ slot,
                                       int rb, int gbase, int k0, int tid) {
  const int r = rb + (tid >> 2);
  const int sseg = (tid & 3) ^ ((r >> 1) & 3);
  unsigned short* lp = slot + (size_t)(rb + ((tid >> 6) << 4)) * 32;
  gload16(gp + (size_t)(gbase + r) * KDIM + k0 + sseg * 8, lp);
}

__global__ __launch_bounds__(512, 1)
void gemm8(const unsigned short* __restrict__ xb, const unsigned short* __restrict__ hb,
           const unsigned short* __restrict__ Wxt, const unsigned short* __restrict__ Wht,
           unsigned short* __restrict__ gxb, unsigned short* __restrict__ ghb,
           const float* __restrict__ bhv) {
  __shared__ __align__(16) unsigned short S[4][2][256][32];  // 4 slots x (A,B) = 128KiB

  const unsigned short* A;
  const unsigned short* Bt;
  unsigned short* Cp;
  const float* bias;
  if (blockIdx.z == 0) { A = xb; Bt = Wxt; Cp = gxb; bias = nullptr; }
  else                 { A = hb; Bt = Wht; Cp = ghb; bias = bhv; }

  // T1 XCD swizzle (bijective; ny=64 %8==0), y-major within chunk.
  int bx = blockIdx.x, by = blockIdx.y;
  {
    const int n = blockIdx.x + 16 * blockIdx.y;
    const int xcd = n & 7, idx = n >> 3;
    const int ych = gridDim.y >> 3;
    bx = idx / ych;
    by = xcd * ych + (idx % ych);
  }
  const int bm = by * BM, bn = bx * BN;

  const int tid = threadIdx.x, w = tid >> 6, lane = tid & 63;
  const int wr = w >> 2, wc = w & 3;          // 2x4 waves; per-wave 128x64 out
  const int m0 = lane & 15, kg = lane >> 4;
  const int koff = (kg ^ ((m0 >> 1) & 3)) << 3;   // matches stageR's seg swizzle

  f32x4 acc[8][4] = {};
  i32x4 afX[8], bfX[4], afY[8], bfY[4];

#define READF(AF, BF, SL)                                                      \
  {                                                                            \
    const unsigned short* Ab = &S[SL][0][0][0];                                \
    const unsigned short* Bb = &S[SL][1][0][0];                                \
    _Pragma("unroll")                                                          \
    for (int i = 0; i < 8; ++i)                                                \
      AF[i] = *(const i32x4*)(Ab + (wr * 128 + i * 16 + m0) * 32 + koff);      \
    _Pragma("unroll")                                                          \
    for (int j = 0; j < 4; ++j)                                                \
      BF[j] = *(const i32x4*)(Bb + (wc * 64 + j * 16 + m0) * 32 + koff);       \
  }

#define MMF(AF, BF)                                                            \
  __builtin_amdgcn_s_setprio(1);                                               \
  _Pragma("unroll")                                                            \
  for (int i = 0; i < 8; ++i)                                                  \
    _Pragma("unroll")                                                          \
    for (int j = 0; j < 4; ++j)                                                \
      mfma_bf16(acc[i][j], AF[i], BF[j]);                                      \
  __builtin_amdgcn_s_setprio(0);

#define STAGE(T)                                                               \
  { const int kk = (T) << 5; const int sl = (T) & 3;                           \
    stageR(A,  &S[sl][0][0][0], 0,   bm, kk, tid);                             \
    stageR(A,  &S[sl][0][0][0], 128, bm, kk, tid);                             \
    stageR(Bt, &S[sl][1][0][0], 0,   bn, kk, tid);                             \
    stageR(Bt, &S[sl][1][0][0], 128, bn, kk, tid); }

  // prologue: stage tiles 0,1,2; retire 0 and 1 (keep tile2's 4); barrier.
  STAGE(0) STAGE(1) STAGE(2)
  asm volatile("s_waitcnt vmcnt(4)" ::: "memory");
  __builtin_amdgcn_s_barrier();
  __builtin_amdgcn_sched_barrier(0);
  READF(afX, bfX, 0)

  // 16 iterations x 2 tiles (X then Y roles), static ping-pong (rule #20).
#pragma unroll 1
  for (int tt = 0; tt < 16; ++tt) {
    const int t0 = tt * 2;
    // ---- tile t0 (compute X, pre-read Y = frags(t0+1)) ----
    if (t0 <= 28) STAGE(t0 + 3)
    READF(afY, bfY, (t0 + 1) & 3)
    MMF(afX, bfX)                       // lgkmcnt(12) auto: Y reads in flight
    if (t0 <= 28)      asm volatile("s_waitcnt vmcnt(4)" ::: "memory");
    __builtin_amdgcn_s_barrier();
    __builtin_amdgcn_sched_barrier(0);
    // ---- tile t1 = t0+1 (compute Y, pre-read X = frags(t0+2)) ----
    const int t1 = t0 + 1;
    if (t1 <= 28) STAGE(t1 + 3)
    if (t1 < 31) READF(afX, bfX, (t1 + 1) & 3)
    MMF(afY, bfY)
    if (t1 <= 28)      asm volatile("s_waitcnt vmcnt(4)" ::: "memory");
    else if (t1 == 29) asm volatile("s_waitcnt vmcnt(0)" ::: "memory");
    if (t1 < 31) {
      __builtin_amdgcn_s_barrier();
      __builtin_amdgcn_sched_barrier(0);
    }
  }

  // ---- LDS-transposed epilogue (S dead == one 256x256 bf16 tile) ----
  __builtin_amdgcn_s_barrier();
  __builtin_amdgcn_sched_barrier(0);
  unsigned short* E = &S[0][0][0][0];   // [256][256] ushort view
  const int rg = kg * 4;
#pragma unroll
  for (int mi = 0; mi < 8; ++mi) {
#pragma unroll
    for (int nj = 0; nj < 4; ++nj) {
      const int col = wc * 64 + nj * 16 + m0;
      const float bv = bias ? bias[bn + col] : 0.0f;
      const int rowb = wr * 128 + mi * 16 + rg;
#pragma unroll
      for (int r = 0; r < 4; ++r) {
        const int row = rowb + r;
        E[row * 256 + (col ^ (((row >> 2) & 3) << 4))] = f2bf(acc[mi][nj][r] + bv);
      }
    }
  }
  __syncthreads();
#pragma unroll
  for (int jj = 0; jj < 16; ++jj) {
    const int row = jj * 16 + (tid >> 5);
    const int c0 = (tid & 31) * 8;
    const int cs = c0 ^ (((row >> 2) & 3) << 4);
    const u16x8 v = *(const u16x8*)&E[row * 256 + cs];
    *(u16x8*)&Cp[(size_t)(bm + row) * NCOLS + bn + c0] = v;
  }
#undef READF
#undef MMF
#undef STAGE
}

// ---- global mask compaction scan ----
__global__ void scan_mask(const int* __restrict__ idd, int* __restrict__ sel,
                          int* __restrict__ mcount) {
  __shared__ int ps[1024];
  const int t = threadIdx.x;
  int loc[16];
  int cnt = 0;
#pragma unroll
  for (int i = 0; i < 16; ++i) {
    const int v = (idd[t * 16 + i] != 0) ? 1 : 0;
    loc[i] = v; cnt += v;
  }
  ps[t] = cnt;
  __syncthreads();
  for (int off = 1; off < 1024; off <<= 1) {
    const int add = (t >= off) ? ps[t - off] : 0;
    __syncthreads();
    ps[t] += add;
    __syncthreads();
  }
  int rank = (t == 0) ? 0 : ps[t - 1];
#pragma unroll
  for (int i = 0; i < 16; ++i)
    if (loc[i]) sel[rank++] = t * 16 + i;
  if (t == 1023) *mcount = ps[1023];
}

// ---- per-batch CSR (deterministic, sorted contributor lists) ----
__global__ void build_csr(const int* __restrict__ idd, const int* __restrict__ idr,
                          const int* __restrict__ idl,
                          int* __restrict__ ofsD, int* __restrict__ ofsR, int* __restrict__ ofsL,
                          int* __restrict__ lstD, int* __restrict__ lstR, int* __restrict__ lstL) {
  __shared__ int sidx[512];
  __shared__ int scan[512];
  const int b = blockIdx.x, t = threadIdx.x;
  const int gb = b << 9;
  const int* const srcs[3] = { idd, idr, idl };
  int* const ofss[3] = { ofsD, ofsR, ofsL };
  int* const lsts[3] = { lstD, lstR, lstL };
  for (int a = 0; a < 3; ++a) {
    sidx[t] = srcs[a][gb + t];
    scan[t] = 0;
    __syncthreads();
    atomicAdd(&scan[sidx[t]], 1);
    __syncthreads();
    int v = scan[t];
    for (int off = 1; off < 512; off <<= 1) {
      const int add = (t >= off) ? scan[t - off] : 0;
      __syncthreads();
      scan[t] += add;
      __syncthreads();
    }
    const int start = scan[t] - v;
    ofss[a][b * 513 + t] = start;
    if (t == 511) ofss[a][b * 513 + 512] = scan[511];
    int pos = start;
    for (int l = 0; l < 512; ++l)
      if (sidx[l] == t) lsts[a][gb + (pos++)] = l;
    __syncthreads();
  }
}

// ---- fused epilogue: gather-add + f-gate + activations + compaction write ----
__global__ __launch_bounds__(256)
void fused_final(const unsigned short* __restrict__ gxb, const unsigned short* __restrict__ ghb,
                 const float* __restrict__ h0, const float* __restrict__ c0,
                 const int* __restrict__ idd, const int* __restrict__ idr,
                 const int* __restrict__ idl,
                 const int* __restrict__ ofsR, const int* __restrict__ lstR,
                 const int* __restrict__ ofsL, const int* __restrict__ lstL,
                 const int* __restrict__ ofsD, const int* __restrict__ lstD,
                 const int* __restrict__ sel, const int* __restrict__ mcount,
                 float* __restrict__ hout, float* __restrict__ cout, int r0) {
  const int r = blockIdx.x;
  const int g = r0 + r;
  const int j = g & 511;
  const int bb = g >> 9;
  const int lbase = (r >> 9) << 9;
  const int ob = bb * 513;
  const int lb = bb << 9;
  const int c = threadIdx.x << 2;

  float a0 = 0.f, a1 = 0.f, a2 = 0.f, a3 = 0.f;
  for (int q = ofsR[ob + j], e = ofsR[ob + j + 1]; q < e; ++q) {
    const int l = lstR[lb + q];
    const u16x4 v = *(const u16x4*)&ghb[(size_t)(lbase + l) * NCOLS + c];
    a0 += bf2f(v[0]); a1 += bf2f(v[1]); a2 += bf2f(v[2]); a3 += bf2f(v[3]);
  }
  for (int q = ofsL[ob + j], e = ofsL[ob + j + 1]; q < e; ++q) {
    const int l = lstL[lb + q];
    const u16x4 v = *(const u16x4*)&ghb[(size_t)(lbase + l) * NCOLS + 1024 + c];
    a0 += bf2f(v[0]); a1 += bf2f(v[1]); a2 += bf2f(v[2]); a3 += bf2f(v[3]);
  }

  const u16x4 fx4 = *(const u16x4*)&gxb[(size_t)r * NCOLS + 3072 + c];
  const float fx0 = bf2f(fx4[0]), fx1 = bf2f(fx4[1]), fx2 = bf2f(fx4[2]), fx3 = bf2f(fx4[3]);
  float fc0 = 0.f, fc1 = 0.f, fc2 = 0.f, fc3 = 0.f;
  for (int q = ofsD[ob + j], e = ofsD[ob + j + 1]; q < e; ++q) {
    const int l = lstD[lb + q];
    const int jr = idr[lb + l], jl = idl[lb + l];
    const u16x4 rv = *(const u16x4*)&ghb[(size_t)(lbase + jr) * NCOLS + 2048 + c];
    const u16x4 lv = *(const u16x4*)&ghb[(size_t)(lbase + jl) * NCOLS + 3072 + c];
    const float4 cc = *(const float4*)&c0[(size_t)(lb + l) * HID + c];
    fc0 += sigmoidf_(fx0 + bf2f(rv[0]) + bf2f(lv[0])) * cc.x;
    fc1 += sigmoidf_(fx1 + bf2f(rv[1]) + bf2f(lv[1])) * cc.y;
    fc2 += sigmoidf_(fx2 + bf2f(rv[2]) + bf2f(lv[2])) * cc.z;
    fc3 += sigmoidf_(fx3 + bf2f(rv[3]) + bf2f(lv[3])) * cc.w;
  }

  const u16x4 vi = *(const u16x4*)&gxb[(size_t)r * NCOLS + c];
  const u16x4 vo = *(const u16x4*)&gxb[(size_t)r * NCOLS + 1024 + c];
  const u16x4 vu = *(const u16x4*)&gxb[(size_t)r * NCOLS + 2048 + c];
  float4 hn, cn;
  {
    const float ig = sigmoidf_(bf2f(vi[0]) + a0), og = sigmoidf_(bf2f(vo[0]));
    cn.x = ig * tanhf(bf2f(vu[0])) + fc0; hn.x = og * tanhf(cn.x);
  }
  {
    const float ig = sigmoidf_(bf2f(vi[1]) + a1), og = sigmoidf_(bf2f(vo[1]));
    cn.y = ig * tanhf(bf2f(vu[1])) + fc1; hn.y = og * tanhf(cn.y);
  }
  {
    const float ig = sigmoidf_(bf2f(vi[2]) + a2), og = sigmoidf_(bf2f(vo[2]));
    cn.z = ig * tanhf(bf2f(vu[2])) + fc2; hn.z = og * tanhf(cn.z);
  }
  {
    const float ig = sigmoidf_(bf2f(vi[3]) + a3), og = sigmoidf_(bf2f(vo[3]));
    cn.w = ig * tanhf(bf2f(vu[3])) + fc3; hn.w = og * tanhf(cn.w);
  }

  if (idd[g] == 0) {
    *(float4*)&hout[(size_t)g * HID + c] = *(const float4*)&h0[(size_t)g * HID + c];
    *(float4*)&cout[(size_t)g * HID + c] = *(const float4*)&c0[(size_t)g * HID + c];
  }
  const int m = *mcount;
  if (g < m) {
    const int o = sel[g];
    *(float4*)&hout[(size_t)o * HID + c] = hn;
    *(float4*)&cout[(size_t)o * HID + c] = cn;
  }
}

extern "C" void kernel_launch(void* const* d_in, const int* in_sizes, int n_in,
                              void* d_out, int out_size, void* d_ws, size_t ws_size,
                              hipStream_t stream) {
  const float* x      = (const float*)d_in[0];
  const float* h0     = (const float*)d_in[1];
  const float* c0     = (const float*)d_in[2];
  const float* W_ioux = (const float*)d_in[3];
  const float* W_iouh = (const float*)d_in[4];
  const float* b_iouh = (const float*)d_in[5];
  const float* W_fx   = (const float*)d_in[6];
  const float* W_fh   = (const float*)d_in[7];
  const float* b_fh   = (const float*)d_in[8];
  const int* idd      = (const int*)d_in[9];
  const int* idr      = (const int*)d_in[10];
  const int* idl      = (const int*)d_in[11];
  float* hout = (float*)d_out;
  float* cout = hout + (size_t)ROWS * HID;

  // fixed region (~17.3 MB)
  char* ws = (char*)d_ws;
  unsigned short* Wxt  = (unsigned short*)(ws);
  unsigned short* Wht  = (unsigned short*)(ws + 8388608u);
  float*          bh   = (float*)(ws + 16777216u);
  int*            sel  = (int*)(ws + 16793600u);
  int*            mcnt = (int*)(ws + 16859136u);
  int*            ofsD = (int*)(ws + 16859392u);
  int*            ofsR = (int*)(ws + 16925184u);
  int*            ofsL = (int*)(ws + 16990976u);
  int*            lstD = (int*)(ws + 17056768u);
  int*            lstR = (int*)(ws + 17122304u);
  int*            lstL = (int*)(ws + 17187840u);
  const size_t    base = 17253376u;

  // chunk size: largest power-of-two divisor of 32 fitting ws (10 MiB per batch)
  int C = 32;
  while (C > 1 && base + 10485760ull * (size_t)C > ws_size) C >>= 1;
  const int R = 512 * C;

  char* p = ws + base;
  unsigned short* xb  = (unsigned short*)p;  p += 1048576ull * C;
  unsigned short* hb  = (unsigned short*)p;  p += 1048576ull * C;
  unsigned short* gxb = (unsigned short*)p;  p += 4194304ull * C;
  unsigned short* ghb = (unsigned short*)p;

  pack_wx<<<dim3(128, 32), dim3(32, 32), 0, stream>>>(W_ioux, W_fx, Wxt);
  pack_wh<<<dim3(128, 32), dim3(32, 32), 0, stream>>>(W_iouh, W_fh, Wht);
  pack_bias<<<4, 1024, 0, stream>>>(b_iouh, b_fh, bh);
  scan_mask<<<1, 1024, 0, stream>>>(idd, sel, mcnt);
  build_csr<<<32, 512, 0, stream>>>(idd, idr, idl, ofsD, ofsR, ofsL, lstD, lstR, lstL);

  for (int b0 = 0; b0 < 32; b0 += C) {
    const size_t r0 = (size_t)b0 * 512;
    convert_bf16<<<R, 256, 0, stream>>>(x + r0 * HID, h0 + r0 * HID, xb, hb);
    gemm8<<<dim3(NCOLS / BN, R / BM, 2), 512, 0, stream>>>(xb, hb, Wxt, Wht, gxb, ghb, bh);
    fused_final<<<R, 256, 0, stream>>>(gxb, ghb, h0, c0, idd, idr, idl,
                                       ofsR, lstR, ofsL, lstL, ofsD, lstD,
                                       sel, mcnt, hout, cout, (int)r0);
  }
}